// Round 3
// baseline (166.110 us; speedup 1.0000x reference)
//
#include <hip/hip_runtime.h>
#include <math.h>
#include <limits.h>

#define BB 2
#define NN 16384
#define MM 4096
#define CCH 16
#define KK 32
#define R2 0.01f
#define EPSV 1e-8f
#define HSTRIDE 36
#define GD 10
#define CPB (GD*GD*GD)          // cells per batch
#define NCELL (BB*CPB)          // 2000
#define WS_NEEDED (16384 + (size_t)BB*NN*16)

__device__ __forceinline__ int cell_of(float x, float y, float z) {
    int cx = min(GD-1, max(0, (int)(x * 10.0f)));
    int cy = min(GD-1, max(0, (int)(y * 10.0f)));
    int cz = min(GD-1, max(0, (int)(z * 10.0f)));
    return (cx*GD + cy)*GD + cz;
}

__global__ void k_zero(int* cnt) {
    int i = blockIdx.x*256 + threadIdx.x;
    if (i < NCELL) cnt[i] = 0;
}

__global__ void k_hist(const float* __restrict__ xyz, int* __restrict__ cnt) {
    int i = blockIdx.x*256 + threadIdx.x;
    if (i >= BB*NN) return;
    const float* p = xyz + (size_t)i*3;
    int b = i >> 14;
    atomicAdd(&cnt[b*CPB + cell_of(p[0], p[1], p[2])], 1);
}

__global__ void k_scan(int* __restrict__ cnt, int* __restrict__ off) {
    __shared__ int sa[2048], sb[2048];
    int t = threadIdx.x;
    for (int j = t; j < 2048; j += 1024) sa[j] = (j < NCELL) ? cnt[j] : 0;
    __syncthreads();
    int* src = sa; int* dst = sb;
    for (int d = 1; d < 2048; d <<= 1) {
        for (int j = t; j < 2048; j += 1024)
            dst[j] = src[j] + ((j >= d) ? src[j-d] : 0);
        __syncthreads();
        int* tmp = src; src = dst; dst = tmp;
    }
    for (int j = t; j <= NCELL; j += 1024) off[j] = (j > 0) ? src[j-1] : 0;
    for (int j = t; j < NCELL; j += 1024) cnt[j] = 0;   // reuse as cursor
}

__global__ void k_scatter(const float* __restrict__ xyz, const int* __restrict__ off,
                          int* __restrict__ cur, float4* __restrict__ pts) {
    int i = blockIdx.x*256 + threadIdx.x;
    if (i >= BB*NN) return;
    const float* p = xyz + (size_t)i*3;
    int b = i >> 14;
    float x = p[0], y = p[1], z = p[2];
    int cell = b*CPB + cell_of(x, y, z);
    int slot = off[cell] + atomicAdd(&cur[cell], 1);
    pts[slot] = make_float4(x, y, z, __int_as_float(i & (NN-1)));
}

__global__ __launch_bounds__(256, 4) void grouper_fused(
    const float* __restrict__ xyz, const float* __restrict__ new_xyz,
    const float* __restrict__ feat,
    const float* __restrict__ w0, const float* __restrict__ b0,
    const float* __restrict__ w1, const float* __restrict__ b1,
    const float* __restrict__ wxyz, const float* __restrict__ bxyz,
    const int* __restrict__ off, const float4* __restrict__ pts,
    int use_grid,
    float* __restrict__ out)
{
    const int lane = threadIdx.x & 63;
    const int wid  = threadIdx.x >> 6;
    const int q    = (blockIdx.x << 2) + wid;
    const int b    = q >> 12;
    const int m    = q & (MM - 1);

    __shared__ int s_idx[4][KK];
    __shared__ __align__(16) float s_h0[4][KK * HSTRIDE];

    const float* xb = xyz + (size_t)b * NN * 3;
    const float qx = new_xyz[((size_t)b*MM + m)*3 + 0];
    const float qy = new_xyz[((size_t)b*MM + m)*3 + 1];
    const float qz = new_xyz[((size_t)b*MM + m)*3 + 2];
    const unsigned long long below = (1ull << lane) - 1ull;

    int nfound = 0, idx0 = 0;
    bool need_full = (use_grid == 0);

    if (use_grid) {
        // ---- gather candidates from <=27 cells, round-robin across lanes ----
        int x0 = max(0, (int)floorf((qx - 0.1f)*10.0f - 1e-3f));
        int x1 = min(GD-1, (int)floorf((qx + 0.1f)*10.0f + 1e-3f));
        int y0 = max(0, (int)floorf((qy - 0.1f)*10.0f - 1e-3f));
        int y1 = min(GD-1, (int)floorf((qy + 0.1f)*10.0f + 1e-3f));
        int z0 = max(0, (int)floorf((qz - 0.1f)*10.0f - 1e-3f));
        int z1 = min(GD-1, (int)floorf((qz + 0.1f)*10.0f + 1e-3f));

        int cand[8];
        #pragma unroll
        for (int j = 0; j < 8; ++j) cand[j] = INT_MAX;
        int nloc = 0, tot = 0;
        bool ovf = false;

        for (int cx = x0; cx <= x1; ++cx)
        for (int cy = y0; cy <= y1; ++cy)
        for (int cz = z0; cz <= z1; ++cz) {
            int cell = b*CPB + (cx*GD + cy)*GD + cz;
            int s = off[cell], e = off[cell+1];
            for (int j = s + ((lane - tot) & 63); j < e; j += 64) {
                float4 pt = pts[j];
                float dx = pt.x - qx, dy = pt.y - qy, dz = pt.z - qz;
                float d2 = dx*dx + dy*dy + dz*dz;
                if (d2 < R2) {
                    int id = __float_as_int(pt.w);
                    bool put = false;
                    #pragma unroll
                    for (int jj = 0; jj < 8; ++jj)
                        if (!put && cand[jj] == INT_MAX) { cand[jj] = id; put = true; }
                    if (put) ++nloc; else ovf = true;
                }
            }
            tot += e - s;
        }

        if (__ballot(ovf) != 0ull) {
            need_full = true;            // capacity exceeded (shouldn't happen) — exact fallback
        } else {
            // ---- total hit count ----
            int C = nloc;
            #pragma unroll
            for (int d = 1; d < 64; d <<= 1) C += __shfl_xor(C, d);

            // ---- threshold T: smallest T with #(idx < T) >= 32  (f(T)==min(C,32)) ----
            int T = NN;   // indices are < NN
            if (C > KK) {
                int lo = 0, hi = NN;
                while (hi - lo > 1) {
                    int mid = (lo + hi) >> 1;
                    int cnt = 0;
                    #pragma unroll
                    for (int j = 0; j < 8; ++j)
                        cnt += __popcll(__ballot(cand[j] < mid));
                    if (cnt >= KK) hi = mid; else lo = mid;
                }
                T = hi;
            }

            // ---- compact selected into s_idx via ballot prefix ----
            int base = 0;
            #pragma unroll
            for (int j = 0; j < 8; ++j) {
                bool sel = cand[j] < T;
                unsigned long long mk = __ballot(sel);
                int pos = base + __popcll(mk & below);
                if (sel && pos < KK) s_idx[wid][pos] = cand[j];
                base += __popcll(mk);
            }
            nfound = min(base, KK);

            // ---- min index for padding / idn ----
            int mn = INT_MAX;
            #pragma unroll
            for (int j = 0; j < 8; ++j) mn = min(mn, cand[j]);
            #pragma unroll
            for (int d = 1; d < 64; d <<= 1) mn = min(mn, __shfl_xor(mn, d));
            idx0 = (nfound > 0) ? mn : 0;

            __builtin_amdgcn_wave_barrier();
            if (lane >= nfound && lane < KK) s_idx[wid][lane] = idx0;
            __builtin_amdgcn_wave_barrier();
        }
    }

    if (need_full) {
        // ---- exact full scan (round-2 path): first K by ascending index ----
        int cnt = 0;
        for (int basep = 0; basep < NN; basep += 256) {
            float d2a[4];
            #pragma unroll
            for (int j = 0; j < 4; ++j) {
                int i = basep + (j << 6) + lane;
                float px = xb[i*3+0], py = xb[i*3+1], pz = xb[i*3+2];
                float dx = px - qx, dy = py - qy, dz = pz - qz;
                d2a[j] = dx*dx + dy*dy + dz*dz;
            }
            #pragma unroll
            for (int j = 0; j < 4; ++j) {
                bool hit = d2a[j] < R2;
                unsigned long long msk = __ballot(hit);
                if (hit) {
                    int pos = cnt + __popcll(msk & below);
                    if (pos < KK) s_idx[wid][pos] = basep + (j << 6) + lane;
                }
                cnt += __popcll(msk);
            }
            if (cnt >= KK) break;
        }
        nfound = cnt < KK ? cnt : KK;
        __builtin_amdgcn_wave_barrier();
        if (lane < KK) {
            int v = 0;
            if (nfound > 0) v = (lane < nfound) ? s_idx[wid][lane] : s_idx[wid][0];
            s_idx[wid][lane] = v;
        }
        __builtin_amdgcn_wave_barrier();
        idx0 = s_idx[wid][0];
    }

    // =================== epilogue (identical math to round 2) ===================
    const int k = lane & 31;
    const int h = lane >> 5;
    const int ik = s_idx[wid][k];

    float px = xb[ik*3+0], py = xb[ik*3+1], pz = xb[ik*3+2];
    float rx = px - qx, ry = py - qy, rz = pz - qz;
    float dist = sqrtf(rx*rx + ry*ry + rz*rz);
    float recip = 1.0f / (dist + EPSV);
    float mult = (float)(1 + KK - nfound);
    float w = recip / ((ik == idx0) ? mult : 1.0f);
    float S = w;
    #pragma unroll
    for (int d = 1; d < 32; d <<= 1) S += __shfl_xor(S, d);
    const float wk = (nfound > 0) ? (w / S) : 0.0f;

    float* hrow_base = &s_h0[wid][0];
    if (h == 0) {
        float* r = hrow_base + k*HSTRIDE;
        r[32] = rx; r[33] = ry; r[34] = rz; r[35] = wk;
    }

    const float* fb = feat + (size_t)b * CCH * NN;
    float g[CCH];
    #pragma unroll
    for (int c = 0; c < CCH; ++c) g[c] = fb[c*NN + ik];

    float h0r[32];
    #pragma unroll
    for (int o = 0; o < 32; ++o) {
        float a0 = b0[o], a1 = 0.f, a2 = 0.f, a3 = 0.f;
        #pragma unroll
        for (int c = 0; c < CCH; c += 4) {
            a0 += w0[o*CCH + c + 0] * g[c + 0];
            a1 += w0[o*CCH + c + 1] * g[c + 1];
            a2 += w0[o*CCH + c + 2] * g[c + 2];
            a3 += w0[o*CCH + c + 3] * g[c + 3];
        }
        h0r[o] = fmaxf((a0 + a1) + (a2 + a3), 0.0f);
    }
    if (h == 0) {
        float4* dst = (float4*)(hrow_base + k*HSTRIDE);
        #pragma unroll
        for (int o = 0; o < 32; o += 4)
            dst[o >> 2] = make_float4(h0r[o], h0r[o+1], h0r[o+2], h0r[o+3]);
    }

    __builtin_amdgcn_wave_barrier();

    float* out2 = out + (size_t)BB*MM*3 + (size_t)b*96*MM;

    {
        const float* wr = w1 + lane*32;
        float w1r[32];
        #pragma unroll
        for (int o = 0; o < 32; o += 4) {
            float4 v4 = *(const float4*)(wr + o);
            w1r[o] = v4.x; w1r[o+1] = v4.y; w1r[o+2] = v4.z; w1r[o+3] = v4.w;
        }
        const float b1O = b1[lane];
        float acc_out = 0.0f;
        #pragma unroll 4
        for (int kk = 0; kk < KK; ++kk) {
            const float* hrow = hrow_base + kk*HSTRIDE;
            const float4* hv = (const float4*)hrow;
            float d0 = 0.f, d1 = 0.f, d2s = 0.f, d3 = 0.f;
            #pragma unroll
            for (int o = 0; o < 32; o += 4) {
                float4 hq = hv[o >> 2];
                d0  += w1r[o+0] * hq.x;
                d1  += w1r[o+1] * hq.y;
                d2s += w1r[o+2] * hq.z;
                d3  += w1r[o+3] * hq.w;
            }
            float dot = ((d0 + d1) + (d2s + d3)) + b1O;
            acc_out += hrow[35] * fmaxf(dot, 0.0f);
        }
        out2[(32 + lane)*MM + m] = acc_out;
    }

    {
        const int c = lane & 31;
        const float wx0 = wxyz[c*3+0], wx1 = wxyz[c*3+1], wx2 = wxyz[c*3+2];
        const float bc = bxyz[c];
        float v = 0.0f;
        #pragma unroll
        for (int kk = 0; kk < 16; ++kk) {
            const float* hr = hrow_base + ((h << 4) + kk)*HSTRIDE;
            float t = bc + wx0*hr[32] + wx1*hr[33] + wx2*hr[34];
            v = fmaxf(v, fmaxf(t, 0.0f));
        }
        v = fmaxf(v, __shfl_xor(v, 32));
        if (h == 0) out2[c*MM + m] = v;
    }

    if (lane == 0) {
        float* o0 = out + ((size_t)b*MM + m)*3;
        o0[0] = qx; o0[1] = qy; o0[2] = qz;
    }
}

extern "C" void kernel_launch(void* const* d_in, const int* in_sizes, int n_in,
                              void* d_out, int out_size, void* d_ws, size_t ws_size,
                              hipStream_t stream) {
    const float* xyz     = (const float*)d_in[0];
    const float* new_xyz = (const float*)d_in[1];
    const float* feat    = (const float*)d_in[2];
    const float* w0      = (const float*)d_in[3];
    const float* b0      = (const float*)d_in[4];
    const float* w1      = (const float*)d_in[5];
    const float* b1      = (const float*)d_in[6];
    const float* wxyz    = (const float*)d_in[7];
    const float* bxyz    = (const float*)d_in[8];
    float* out = (float*)d_out;

    int* cnt = (int*)d_ws;
    int* off = (int*)d_ws + 2048;
    float4* pts = (float4*)((char*)d_ws + 16384);
    const int use_grid = (d_ws != nullptr && ws_size >= WS_NEEDED) ? 1 : 0;

    if (use_grid) {
        hipLaunchKernelGGL(k_zero, dim3((NCELL+255)/256), dim3(256), 0, stream, cnt);
        hipLaunchKernelGGL(k_hist, dim3((BB*NN+255)/256), dim3(256), 0, stream, xyz, cnt);
        hipLaunchKernelGGL(k_scan, dim3(1), dim3(1024), 0, stream, cnt, off);
        hipLaunchKernelGGL(k_scatter, dim3((BB*NN+255)/256), dim3(256), 0, stream, xyz, off, cnt, pts);
    }
    hipLaunchKernelGGL(grouper_fused, dim3((BB*MM)/4), dim3(256), 0, stream,
                       xyz, new_xyz, feat, w0, b0, w1, b1, wxyz, bxyz,
                       off, pts, use_grid, out);
}

// Round 4
// 163.287 us; speedup vs baseline: 1.0173x; 1.0173x over previous
//
#include <hip/hip_runtime.h>
#include <math.h>
#include <limits.h>

#define BB 2
#define NN 16384
#define MM 4096
#define CCH 16
#define KK 32
#define R2 0.01f
#define EPSV 1e-8f
#define HSTRIDE 36
#define GD 10
#define CPB (GD*GD*GD)
#define CAP 56                          // bucket capacity; Poisson(16.4) tail ~1e-12
#define NCELL (BB*CPB)                  // 2000
#define BUCKET_OFF 16384                // byte offset of buckets in ws
#define WS_NEEDED (BUCKET_OFF + (size_t)NCELL*CAP*16)

__device__ __forceinline__ int cell_of(float x, float y, float z) {
    int cx = min(GD-1, max(0, (int)(x * 10.0f)));
    int cy = min(GD-1, max(0, (int)(y * 10.0f)));
    int cz = min(GD-1, max(0, (int)(z * 10.0f)));
    return (cx*GD + cy)*GD + cz;
}

// ws layout: [0]=ovf flag, [64..64+8000)=cnt[2000], [16384..)=float4 buckets[2000][CAP]
__global__ void k_scatter(const float* __restrict__ xyz, int* __restrict__ cnt,
                          int* __restrict__ ovf, float4* __restrict__ buckets) {
    int i = blockIdx.x*256 + threadIdx.x;
    if (i >= BB*NN) return;
    const float* p = xyz + (size_t)i*3;
    int b = i >> 14;
    float x = p[0], y = p[1], z = p[2];
    int cell = b*CPB + cell_of(x, y, z);
    int slot = atomicAdd(&cnt[cell], 1);
    if (slot < CAP)
        buckets[(size_t)cell*CAP + slot] = make_float4(x, y, z, __int_as_float(i & (NN-1)));
    else
        *ovf = 1;
}

__global__ __launch_bounds__(256, 4) void grouper_fused(
    const float* __restrict__ xyz, const float* __restrict__ new_xyz,
    const float* __restrict__ feat,
    const float* __restrict__ w0, const float* __restrict__ b0,
    const float* __restrict__ w1, const float* __restrict__ b1,
    const float* __restrict__ wxyz, const float* __restrict__ bxyz,
    const int* __restrict__ cnt, const int* __restrict__ ovf,
    const float4* __restrict__ buckets,
    int use_grid,
    float* __restrict__ out)
{
    const int lane = threadIdx.x & 63;
    const int wid  = threadIdx.x >> 6;
    const int q    = (blockIdx.x << 2) + wid;
    const int b    = q >> 12;
    const int m    = q & (MM - 1);

    __shared__ int s_idx[4][KK];
    __shared__ __align__(16) float s_h0[4][KK * HSTRIDE];

    const float* xb = xyz + (size_t)b * NN * 3;
    const float qx = new_xyz[((size_t)b*MM + m)*3 + 0];
    const float qy = new_xyz[((size_t)b*MM + m)*3 + 1];
    const float qz = new_xyz[((size_t)b*MM + m)*3 + 2];
    const unsigned long long below = (1ull << lane) - 1ull;

    int nfound = 0, idx0 = 0;
    bool need_full = (use_grid == 0) || (use_grid && ovf[0] != 0);

    if (!need_full) {
        int x0 = max(0, (int)floorf((qx - 0.1f)*10.0f - 1e-3f));
        int x1 = min(GD-1, (int)floorf((qx + 0.1f)*10.0f + 1e-3f));
        int y0 = max(0, (int)floorf((qy - 0.1f)*10.0f - 1e-3f));
        int y1 = min(GD-1, (int)floorf((qy + 0.1f)*10.0f + 1e-3f));
        int z0 = max(0, (int)floorf((qz - 0.1f)*10.0f - 1e-3f));
        int z1 = min(GD-1, (int)floorf((qz + 0.1f)*10.0f + 1e-3f));

        int cand[8];
        #pragma unroll
        for (int j = 0; j < 8; ++j) cand[j] = INT_MAX;
        int nloc = 0, tot = 0;
        bool ovfl = false;

        for (int cx = x0; cx <= x1; ++cx)
        for (int cy = y0; cy <= y1; ++cy)
        for (int cz = z0; cz <= z1; ++cz) {
            int cell = b*CPB + (cx*GD + cy)*GD + cz;
            int cc = min(cnt[cell], CAP);
            const float4* bk = buckets + (size_t)cell*CAP;
            for (int j = (lane - tot) & 63; j < cc; j += 64) {
                float4 pt = bk[j];
                float dx = pt.x - qx, dy = pt.y - qy, dz = pt.z - qz;
                float d2 = dx*dx + dy*dy + dz*dz;
                if (d2 < R2) {
                    int id = __float_as_int(pt.w);
                    bool put = false;
                    #pragma unroll
                    for (int jj = 0; jj < 8; ++jj)
                        if (!put && cand[jj] == INT_MAX) { cand[jj] = id; put = true; }
                    if (put) ++nloc; else ovfl = true;
                }
            }
            tot += cc;
        }

        if (__ballot(ovfl) != 0ull) {
            need_full = true;   // per-lane candidate overflow — exact fallback
        } else {
            int C = nloc;
            #pragma unroll
            for (int d = 1; d < 64; d <<= 1) C += __shfl_xor(C, d);

            // smallest T with #(idx < T) >= K ; distinct indices => exactly K selected
            int T = NN;
            if (C > KK) {
                int lo = 0, hi = NN;
                while (hi - lo > 1) {
                    int mid = (lo + hi) >> 1;
                    int c2 = 0;
                    #pragma unroll
                    for (int j = 0; j < 8; ++j)
                        c2 += __popcll(__ballot(cand[j] < mid));
                    if (c2 >= KK) hi = mid; else lo = mid;
                }
                T = hi;
            }

            int base = 0;
            #pragma unroll
            for (int j = 0; j < 8; ++j) {
                bool sel = cand[j] < T;
                unsigned long long mk = __ballot(sel);
                int pos = base + __popcll(mk & below);
                if (sel && pos < KK) s_idx[wid][pos] = cand[j];
                base += __popcll(mk);
            }
            nfound = min(base, KK);

            int mn = INT_MAX;
            #pragma unroll
            for (int j = 0; j < 8; ++j) mn = min(mn, cand[j]);
            #pragma unroll
            for (int d = 1; d < 64; d <<= 1) mn = min(mn, __shfl_xor(mn, d));
            idx0 = (nfound > 0) ? mn : 0;

            __builtin_amdgcn_wave_barrier();
            if (lane >= nfound && lane < KK) s_idx[wid][lane] = idx0;
            __builtin_amdgcn_wave_barrier();
        }
    }

    if (need_full) {
        int cntf = 0;
        for (int basep = 0; basep < NN; basep += 256) {
            float d2a[4];
            #pragma unroll
            for (int j = 0; j < 4; ++j) {
                int i = basep + (j << 6) + lane;
                float px = xb[i*3+0], py = xb[i*3+1], pz = xb[i*3+2];
                float dx = px - qx, dy = py - qy, dz = pz - qz;
                d2a[j] = dx*dx + dy*dy + dz*dz;
            }
            #pragma unroll
            for (int j = 0; j < 4; ++j) {
                bool hit = d2a[j] < R2;
                unsigned long long msk = __ballot(hit);
                if (hit) {
                    int pos = cntf + __popcll(msk & below);
                    if (pos < KK) s_idx[wid][pos] = basep + (j << 6) + lane;
                }
                cntf += __popcll(msk);
            }
            if (cntf >= KK) break;
        }
        nfound = cntf < KK ? cntf : KK;
        __builtin_amdgcn_wave_barrier();
        if (lane < KK) {
            int v = 0;
            if (nfound > 0) v = (lane < nfound) ? s_idx[wid][lane] : s_idx[wid][0];
            s_idx[wid][lane] = v;
        }
        __builtin_amdgcn_wave_barrier();
        idx0 = s_idx[wid][0];
    }

    // =================== epilogue ===================
    const int k = lane & 31;
    const int h = lane >> 5;
    const int ik = s_idx[wid][k];

    float px = xb[ik*3+0], py = xb[ik*3+1], pz = xb[ik*3+2];
    float rx = px - qx, ry = py - qy, rz = pz - qz;
    float dist = sqrtf(rx*rx + ry*ry + rz*rz);
    float recip = 1.0f / (dist + EPSV);
    float mult = (float)(1 + KK - nfound);
    float w = recip / ((ik == idx0) ? mult : 1.0f);
    float S = w;
    #pragma unroll
    for (int d = 1; d < 32; d <<= 1) S += __shfl_xor(S, d);
    const float wk = (nfound > 0) ? (w / S) : 0.0f;

    float* hrow_base = &s_h0[wid][0];
    if (h == 0) {
        float* r = hrow_base + k*HSTRIDE;
        r[32] = rx; r[33] = ry; r[34] = rz; r[35] = wk;
    }

    const float* fb = feat + (size_t)b * CCH * NN;
    float g[CCH];
    #pragma unroll
    for (int c = 0; c < CCH; ++c) g[c] = fb[c*NN + ik];

    // h0 split across halves: half h computes channels [16h, 16h+16) for its k
    const int chb = h << 4;
    float h0r[16];
    #pragma unroll
    for (int o = 0; o < 16; ++o) {
        const int O = chb + o;
        float a0 = b0[O], a1 = 0.f, a2 = 0.f, a3 = 0.f;
        #pragma unroll
        for (int c = 0; c < CCH; c += 4) {
            a0 += w0[O*CCH + c + 0] * g[c + 0];
            a1 += w0[O*CCH + c + 1] * g[c + 1];
            a2 += w0[O*CCH + c + 2] * g[c + 2];
            a3 += w0[O*CCH + c + 3] * g[c + 3];
        }
        h0r[o] = fmaxf((a0 + a1) + (a2 + a3), 0.0f);
    }
    {
        float4* dst = (float4*)(hrow_base + k*HSTRIDE + chb);
        #pragma unroll
        for (int o = 0; o < 16; o += 4)
            dst[o >> 2] = make_float4(h0r[o], h0r[o+1], h0r[o+2], h0r[o+3]);
    }

    __builtin_amdgcn_wave_barrier();

    float* out2 = out + (size_t)BB*MM*3 + (size_t)b*96*MM;

    {   // layer 1 + weighted sum-pool: lane = output channel O
        const float* wr = w1 + lane*32;
        float w1r[32];
        #pragma unroll
        for (int o = 0; o < 32; o += 4) {
            float4 v4 = *(const float4*)(wr + o);
            w1r[o] = v4.x; w1r[o+1] = v4.y; w1r[o+2] = v4.z; w1r[o+3] = v4.w;
        }
        const float b1O = b1[lane];
        float acc_out = 0.0f;
        #pragma unroll 4
        for (int kk = 0; kk < KK; ++kk) {
            const float* hrow = hrow_base + kk*HSTRIDE;
            const float4* hv = (const float4*)hrow;
            float d0 = 0.f, d1 = 0.f, d2s = 0.f, d3 = 0.f;
            #pragma unroll
            for (int o = 0; o < 32; o += 4) {
                float4 hq = hv[o >> 2];
                d0  += w1r[o+0] * hq.x;
                d1  += w1r[o+1] * hq.y;
                d2s += w1r[o+2] * hq.z;
                d3  += w1r[o+3] * hq.w;
            }
            float dot = ((d0 + d1) + (d2s + d3)) + b1O;
            acc_out += hrow[35] * fmaxf(dot, 0.0f);
        }
        out2[(32 + lane)*MM + m] = acc_out;
    }

    {   // xyz branch: lane = channel c, halves split k, max-pool
        const int c = lane & 31;
        const float wx0 = wxyz[c*3+0], wx1 = wxyz[c*3+1], wx2 = wxyz[c*3+2];
        const float bc = bxyz[c];
        float v = 0.0f;
        #pragma unroll
        for (int kk = 0; kk < 16; ++kk) {
            const float* hr = hrow_base + ((h << 4) + kk)*HSTRIDE;
            float t = bc + wx0*hr[32] + wx1*hr[33] + wx2*hr[34];
            v = fmaxf(v, fmaxf(t, 0.0f));
        }
        v = fmaxf(v, __shfl_xor(v, 32));
        if (h == 0) out2[c*MM + m] = v;
    }

    if (lane == 0) {
        float* o0 = out + ((size_t)b*MM + m)*3;
        o0[0] = qx; o0[1] = qy; o0[2] = qz;
    }
}

extern "C" void kernel_launch(void* const* d_in, const int* in_sizes, int n_in,
                              void* d_out, int out_size, void* d_ws, size_t ws_size,
                              hipStream_t stream) {
    const float* xyz     = (const float*)d_in[0];
    const float* new_xyz = (const float*)d_in[1];
    const float* feat    = (const float*)d_in[2];
    const float* w0      = (const float*)d_in[3];
    const float* b0      = (const float*)d_in[4];
    const float* w1      = (const float*)d_in[5];
    const float* b1      = (const float*)d_in[6];
    const float* wxyz    = (const float*)d_in[7];
    const float* bxyz    = (const float*)d_in[8];
    float* out = (float*)d_out;

    int* ovf = (int*)d_ws;
    int* cnt = (int*)((char*)d_ws + 64);
    float4* buckets = (float4*)((char*)d_ws + BUCKET_OFF);
    const int use_grid = (d_ws != nullptr && ws_size >= WS_NEEDED) ? 1 : 0;

    if (use_grid) {
        hipMemsetAsync(d_ws, 0, BUCKET_OFF, stream);   // ovf + cnt
        hipLaunchKernelGGL(k_scatter, dim3((BB*NN+255)/256), dim3(256), 0, stream,
                           xyz, cnt, ovf, buckets);
    }
    hipLaunchKernelGGL(grouper_fused, dim3((BB*MM)/4), dim3(256), 0, stream,
                       xyz, new_xyz, feat, w0, b0, w1, b1, wxyz, bxyz,
                       cnt, ovf, buckets, use_grid, out);
}

// Round 5
// 141.657 us; speedup vs baseline: 1.1726x; 1.1527x over previous
//
#include <hip/hip_runtime.h>
#include <math.h>
#include <limits.h>

#define BB 2
#define NN 16384
#define MM 4096
#define CCH 16
#define KK 32
#define R2 0.01f
#define EPSV 1e-8f
#define GD 10
#define CPB (GD*GD*GD)
#define CAP 56
#define NCELL (BB*CPB)                  // 2000
#define BUCKET_OFF 16384
#define FEATT_OFF (2*1024*1024)
#define WS_GRID (BUCKET_OFF + (size_t)NCELL*CAP*16)     // ~1.81 MB
#define WS_FT   (FEATT_OFF + (size_t)BB*NN*CCH*4)       // 4.19 MB

typedef __attribute__((ext_vector_type(8))) short short8;
typedef __attribute__((ext_vector_type(4))) float v4f;

__device__ __forceinline__ short f2bf(float f) {       // RNE float->bf16
    unsigned u = __float_as_uint(f);
    unsigned r = u + 0x7FFFu + ((u >> 16) & 1u);
    return (short)(r >> 16);
}

__device__ __forceinline__ int cell_of(float x, float y, float z) {
    int cx = min(GD-1, max(0, (int)(x * 10.0f)));
    int cy = min(GD-1, max(0, (int)(y * 10.0f)));
    int cz = min(GD-1, max(0, (int)(z * 10.0f)));
    return (cx*GD + cy)*GD + cz;
}

// ws: [0]=ovf, [64..8064)=cnt[2000], [16384..)=buckets, [2MB..)=featT [B*N][16]
__global__ void k_scatter(const float* __restrict__ xyz, const float* __restrict__ feat,
                          int* __restrict__ cnt, int* __restrict__ ovf,
                          float4* __restrict__ buckets, float4* __restrict__ featT,
                          int use_ft) {
    int i = blockIdx.x*256 + threadIdx.x;
    if (i >= BB*NN) return;
    const float* p = xyz + (size_t)i*3;
    int b = i >> 14;
    int n = i & (NN-1);
    float x = p[0], y = p[1], z = p[2];
    int cell = b*CPB + cell_of(x, y, z);
    int slot = atomicAdd(&cnt[cell], 1);
    if (slot < CAP)
        buckets[(size_t)cell*CAP + slot] = make_float4(x, y, z, __int_as_float(n));
    else
        *ovf = 1;
    if (use_ft) {
        const float* fb = feat + (size_t)b*CCH*NN + n;
        #pragma unroll
        for (int c4 = 0; c4 < 4; ++c4) {
            float4 t = make_float4(fb[(c4*4+0)*NN], fb[(c4*4+1)*NN],
                                   fb[(c4*4+2)*NN], fb[(c4*4+3)*NN]);
            featT[(size_t)i*4 + c4] = t;
        }
    }
}

__global__ __launch_bounds__(256, 4) void grouper_fused(
    const float* __restrict__ xyz, const float* __restrict__ new_xyz,
    const float* __restrict__ feat,
    const float* __restrict__ w0, const float* __restrict__ b0,
    const float* __restrict__ w1, const float* __restrict__ b1,
    const float* __restrict__ wxyz, const float* __restrict__ bxyz,
    const int* __restrict__ cnt, const int* __restrict__ ovf,
    const float4* __restrict__ buckets, const float4* __restrict__ featT,
    int use_grid, int use_ft,
    float* __restrict__ out)
{
    const int lane = threadIdx.x & 63;
    const int wid  = threadIdx.x >> 6;
    const int q    = (blockIdx.x << 2) + wid;
    const int b    = q >> 12;
    const int m    = q & (MM - 1);

    __shared__ int s_idx[4][KK];
    __shared__ float4 s_rel[4][KK];     // xyz = rel, w = wk

    const float* xb = xyz + (size_t)b * NN * 3;
    const float qx = new_xyz[((size_t)b*MM + m)*3 + 0];
    const float qy = new_xyz[((size_t)b*MM + m)*3 + 1];
    const float qz = new_xyz[((size_t)b*MM + m)*3 + 2];
    const unsigned long long below = (1ull << lane) - 1ull;

    int nfound = 0, idx0 = 0;
    bool need_full = (use_grid == 0) || (use_grid && ovf[0] != 0);

    if (!need_full) {
        int x0 = max(0, (int)floorf((qx - 0.1f)*10.0f - 1e-3f));
        int x1 = min(GD-1, (int)floorf((qx + 0.1f)*10.0f + 1e-3f));
        int y0 = max(0, (int)floorf((qy - 0.1f)*10.0f - 1e-3f));
        int y1 = min(GD-1, (int)floorf((qy + 0.1f)*10.0f + 1e-3f));
        int z0 = max(0, (int)floorf((qz - 0.1f)*10.0f - 1e-3f));
        int z1 = min(GD-1, (int)floorf((qz + 0.1f)*10.0f + 1e-3f));

        int cand[8];
        #pragma unroll
        for (int j = 0; j < 8; ++j) cand[j] = INT_MAX;
        int nloc = 0, tot = 0;
        bool ovfl = false;

        for (int cx = x0; cx <= x1; ++cx)
        for (int cy = y0; cy <= y1; ++cy)
        for (int cz = z0; cz <= z1; ++cz) {
            int cell = b*CPB + (cx*GD + cy)*GD + cz;
            int cc = min(cnt[cell], CAP);
            const float4* bk = buckets + (size_t)cell*CAP;
            for (int j = (lane - tot) & 63; j < cc; j += 64) {
                float4 pt = bk[j];
                float dx = pt.x - qx, dy = pt.y - qy, dz = pt.z - qz;
                float d2 = dx*dx + dy*dy + dz*dz;
                if (d2 < R2) {
                    int id = __float_as_int(pt.w);
                    bool put = false;
                    #pragma unroll
                    for (int jj = 0; jj < 8; ++jj)
                        if (!put && cand[jj] == INT_MAX) { cand[jj] = id; put = true; }
                    if (put) ++nloc; else ovfl = true;
                }
            }
            tot += cc;
        }

        if (__ballot(ovfl) != 0ull) {
            need_full = true;
        } else {
            int C = nloc;
            #pragma unroll
            for (int d = 1; d < 64; d <<= 1) C += __shfl_xor(C, d);

            int T = NN;
            if (C > KK) {
                int lo = 0, hi = NN;
                while (hi - lo > 1) {
                    int mid = (lo + hi) >> 1;
                    int c2 = 0;
                    #pragma unroll
                    for (int j = 0; j < 8; ++j)
                        c2 += __popcll(__ballot(cand[j] < mid));
                    if (c2 >= KK) hi = mid; else lo = mid;
                }
                T = hi;
            }

            int base = 0;
            #pragma unroll
            for (int j = 0; j < 8; ++j) {
                bool sel = cand[j] < T;
                unsigned long long mk = __ballot(sel);
                int pos = base + __popcll(mk & below);
                if (sel && pos < KK) s_idx[wid][pos] = cand[j];
                base += __popcll(mk);
            }
            nfound = min(base, KK);

            int mn = INT_MAX;
            #pragma unroll
            for (int j = 0; j < 8; ++j) mn = min(mn, cand[j]);
            #pragma unroll
            for (int d = 1; d < 64; d <<= 1) mn = min(mn, __shfl_xor(mn, d));
            idx0 = (nfound > 0) ? mn : 0;

            __builtin_amdgcn_wave_barrier();
            if (lane >= nfound && lane < KK) s_idx[wid][lane] = idx0;
            __builtin_amdgcn_wave_barrier();
        }
    }

    if (need_full) {
        int cntf = 0;
        for (int basep = 0; basep < NN; basep += 256) {
            float d2a[4];
            #pragma unroll
            for (int j = 0; j < 4; ++j) {
                int i = basep + (j << 6) + lane;
                float px = xb[i*3+0], py = xb[i*3+1], pz = xb[i*3+2];
                float dx = px - qx, dy = py - qy, dz = pz - qz;
                d2a[j] = dx*dx + dy*dy + dz*dz;
            }
            #pragma unroll
            for (int j = 0; j < 4; ++j) {
                bool hit = d2a[j] < R2;
                unsigned long long msk = __ballot(hit);
                if (hit) {
                    int pos = cntf + __popcll(msk & below);
                    if (pos < KK) s_idx[wid][pos] = basep + (j << 6) + lane;
                }
                cntf += __popcll(msk);
            }
            if (cntf >= KK) break;
        }
        nfound = cntf < KK ? cntf : KK;
        __builtin_amdgcn_wave_barrier();
        if (lane < KK) {
            int v = 0;
            if (nfound > 0) v = (lane < nfound) ? s_idx[wid][lane] : s_idx[wid][0];
            s_idx[wid][lane] = v;
        }
        __builtin_amdgcn_wave_barrier();
        idx0 = s_idx[wid][0];
    }

    // ---------- rel coords + normalized weights (k = lane&31) ----------
    {
        const int k = lane & 31;
        const int h = lane >> 5;
        const int ik = s_idx[wid][k];
        float px = xb[ik*3+0], py = xb[ik*3+1], pz = xb[ik*3+2];
        float rx = px - qx, ry = py - qy, rz = pz - qz;
        float dist = sqrtf(rx*rx + ry*ry + rz*rz);
        float recip = 1.0f / (dist + EPSV);
        float mult = (float)(1 + KK - nfound);
        float w = recip / ((ik == idx0) ? mult : 1.0f);
        float S = w;
        #pragma unroll
        for (int d = 1; d < 32; d <<= 1) S += __shfl_xor(S, d);
        float wk = (nfound > 0) ? (w / S) : 0.0f;
        if (h == 0) s_rel[wid][k] = make_float4(rx, ry, rz, wk);
    }
    __builtin_amdgcn_wave_barrier();

    // ---------- MFMA MLP: lane = (l15, quad) ----------
    const int l15 = lane & 15;
    const int quad = lane >> 4;
    const int ik0 = s_idx[wid][l15];
    const int ik1 = s_idx[wid][16 + l15];

    float g0[CCH], g1[CCH];
    if (use_ft) {
        const float4* f0 = featT + ((size_t)(b*NN + ik0)) * 4;
        const float4* f1 = featT + ((size_t)(b*NN + ik1)) * 4;
        #pragma unroll
        for (int c4 = 0; c4 < 4; ++c4) {
            float4 a = f0[c4], c = f1[c4];
            g0[c4*4+0] = a.x; g0[c4*4+1] = a.y; g0[c4*4+2] = a.z; g0[c4*4+3] = a.w;
            g1[c4*4+0] = c.x; g1[c4*4+1] = c.y; g1[c4*4+2] = c.z; g1[c4*4+3] = c.w;
        }
    } else {
        const float* fb = feat + (size_t)b * CCH * NN;
        #pragma unroll
        for (int c = 0; c < CCH; ++c) { g0[c] = fb[c*NN + ik0]; g1[c] = fb[c*NN + ik1]; }
    }

    // h0 channels [8q, 8q+8) for both neighbors -> A fragments (no transpose)
    short8 A0, A1;
    #pragma unroll
    for (int j = 0; j < 8; ++j) {
        const int o = (quad << 3) + j;
        const float* wr = w0 + o*CCH;
        float a0 = 0.f, a1 = 0.f;
        #pragma unroll
        for (int c = 0; c < CCH; ++c) { a0 += wr[c]*g0[c]; a1 += wr[c]*g1[c]; }
        float bo = b0[o];
        A0[j] = f2bf(fmaxf(a0 + bo, 0.0f));
        A1[j] = f2bf(fmaxf(a1 + bo, 0.0f));
    }

    // B fragments: w1[16u+l15][8q..8q+8)
    short8 Bf[4];
    #pragma unroll
    for (int u = 0; u < 4; ++u) {
        const float* wr = w1 + ((u << 4) + l15)*32 + (quad << 3);
        float4 p = *(const float4*)(wr);
        float4 r = *(const float4*)(wr + 4);
        short8 bb;
        bb[0]=f2bf(p.x); bb[1]=f2bf(p.y); bb[2]=f2bf(p.z); bb[3]=f2bf(p.w);
        bb[4]=f2bf(r.x); bb[5]=f2bf(r.y); bb[6]=f2bf(r.z); bb[7]=f2bf(r.w);
        Bf[u] = bb;
    }

    v4f zero4 = {0.f, 0.f, 0.f, 0.f};
    v4f D[2][4];
    #pragma unroll
    for (int u = 0; u < 4; ++u) {
        D[0][u] = __builtin_amdgcn_mfma_f32_16x16x32_bf16(A0, Bf[u], zero4, 0, 0, 0);
        D[1][u] = __builtin_amdgcn_mfma_f32_16x16x32_bf16(A1, Bf[u], zero4, 0, 0, 0);
    }

    // wk for this lane's 8 rows: k = 16t + 4*quad + r
    float wkv[2][4];
    #pragma unroll
    for (int t = 0; t < 2; ++t)
        #pragma unroll
        for (int r = 0; r < 4; ++r)
            wkv[t][r] = s_rel[wid][16*t + (quad << 2) + r].w;

    float* out2 = out + (size_t)BB*MM*3 + (size_t)b*96*MM;

    float Su[4];
    #pragma unroll
    for (int u = 0; u < 4; ++u) {
        const float b1O = b1[(u << 4) + l15];
        float s = 0.f;
        #pragma unroll
        for (int t = 0; t < 2; ++t)
            #pragma unroll
            for (int r = 0; r < 4; ++r)
                s += wkv[t][r] * fmaxf(D[t][u][r] + b1O, 0.0f);
        s += __shfl_xor(s, 16);
        s += __shfl_xor(s, 32);
        Su[u] = s;
    }
    float sout = (quad == 0) ? Su[0] : (quad == 1) ? Su[1] : (quad == 2) ? Su[2] : Su[3];
    out2[(32 + lane)*MM + m] = sout;   // O = 16*quad + l15 = lane

    // ---------- xyz branch: lane = channel c, halves split k, max-pool ----------
    {
        const int c = lane & 31;
        const int h = lane >> 5;
        const float wx0 = wxyz[c*3+0], wx1 = wxyz[c*3+1], wx2 = wxyz[c*3+2];
        const float bc = bxyz[c];
        float v = 0.0f;
        #pragma unroll
        for (int kk = 0; kk < 16; ++kk) {
            float4 hr = s_rel[wid][(h << 4) + kk];
            float t = bc + wx0*hr.x + wx1*hr.y + wx2*hr.z;
            v = fmaxf(v, fmaxf(t, 0.0f));
        }
        v = fmaxf(v, __shfl_xor(v, 32));
        if (h == 0) out2[c*MM + m] = v;
    }

    if (lane == 0) {
        float* o0 = out + ((size_t)b*MM + m)*3;
        o0[0] = qx; o0[1] = qy; o0[2] = qz;
    }
}

extern "C" void kernel_launch(void* const* d_in, const int* in_sizes, int n_in,
                              void* d_out, int out_size, void* d_ws, size_t ws_size,
                              hipStream_t stream) {
    const float* xyz     = (const float*)d_in[0];
    const float* new_xyz = (const float*)d_in[1];
    const float* feat    = (const float*)d_in[2];
    const float* w0      = (const float*)d_in[3];
    const float* b0      = (const float*)d_in[4];
    const float* w1      = (const float*)d_in[5];
    const float* b1      = (const float*)d_in[6];
    const float* wxyz    = (const float*)d_in[7];
    const float* bxyz    = (const float*)d_in[8];
    float* out = (float*)d_out;

    int* ovf = (int*)d_ws;
    int* cnt = (int*)((char*)d_ws + 64);
    float4* buckets = (float4*)((char*)d_ws + BUCKET_OFF);
    float4* featT   = (float4*)((char*)d_ws + FEATT_OFF);
    const int use_grid = (d_ws != nullptr && ws_size >= WS_GRID) ? 1 : 0;
    const int use_ft   = (d_ws != nullptr && ws_size >= WS_FT) ? 1 : 0;

    if (use_grid) {
        hipMemsetAsync(d_ws, 0, BUCKET_OFF, stream);
        hipLaunchKernelGGL(k_scatter, dim3((BB*NN+255)/256), dim3(256), 0, stream,
                           xyz, feat, cnt, ovf, buckets, featT, use_ft);
    }
    hipLaunchKernelGGL(grouper_fused, dim3((BB*MM)/4), dim3(256), 0, stream,
                       xyz, new_xyz, feat, w0, b0, w1, b1, wxyz, bxyz,
                       cnt, ovf, buckets, featT, use_grid, use_ft, out);
}

// Round 6
// 126.456 us; speedup vs baseline: 1.3136x; 1.1202x over previous
//
#include <hip/hip_runtime.h>
#include <math.h>
#include <limits.h>

#define BB 2
#define NN 16384
#define MM 4096
#define CCH 16
#define KK 32
#define R2 0.01f
#define EPSV 1e-8f
#define GD 10
#define CPB (GD*GD*GD)
#define CAP 56
#define NCELL (BB*CPB)                  // 2000
#define BUCKET_OFF 16384
#define FEATT_OFF (2*1024*1024)
#define WS_GRID (BUCKET_OFF + (size_t)NCELL*CAP*16)     // ~1.81 MB
#define WS_FT   (FEATT_OFF + (size_t)BB*NN*CCH*4)       // 4.19 MB
#define NDW 512                          // bitmap dwords per wave (16384 bits)

typedef __attribute__((ext_vector_type(8))) short short8;
typedef __attribute__((ext_vector_type(4))) float v4f;

__device__ __forceinline__ short f2bf(float f) {       // RNE float->bf16
    unsigned u = __float_as_uint(f);
    unsigned r = u + 0x7FFFu + ((u >> 16) & 1u);
    return (short)(r >> 16);
}

__device__ __forceinline__ int cell_of(float x, float y, float z) {
    int cx = min(GD-1, max(0, (int)(x * 10.0f)));
    int cy = min(GD-1, max(0, (int)(y * 10.0f)));
    int cz = min(GD-1, max(0, (int)(z * 10.0f)));
    return (cx*GD + cy)*GD + cz;
}

// ws: [0]=ovf, [64..8064)=cnt[2000], [16384..)=buckets, [2MB..)=featT [B*N][16]
__global__ void k_scatter(const float* __restrict__ xyz, const float* __restrict__ feat,
                          int* __restrict__ cnt, int* __restrict__ ovf,
                          float4* __restrict__ buckets, float4* __restrict__ featT,
                          int use_ft) {
    int i = blockIdx.x*256 + threadIdx.x;
    if (i >= BB*NN) return;
    const float* p = xyz + (size_t)i*3;
    int b = i >> 14;
    int n = i & (NN-1);
    float x = p[0], y = p[1], z = p[2];
    int cell = b*CPB + cell_of(x, y, z);
    int slot = atomicAdd(&cnt[cell], 1);
    if (slot < CAP)
        buckets[(size_t)cell*CAP + slot] = make_float4(x, y, z, __int_as_float(n));
    else
        *ovf = 1;
    if (use_ft) {
        const float* fb = feat + (size_t)b*CCH*NN + n;
        #pragma unroll
        for (int c4 = 0; c4 < 4; ++c4) {
            float4 t = make_float4(fb[(c4*4+0)*NN], fb[(c4*4+1)*NN],
                                   fb[(c4*4+2)*NN], fb[(c4*4+3)*NN]);
            featT[(size_t)i*4 + c4] = t;
        }
    }
}

__global__ __launch_bounds__(256, 4) void grouper_fused(
    const float* __restrict__ xyz, const float* __restrict__ new_xyz,
    const float* __restrict__ feat,
    const float* __restrict__ w0, const float* __restrict__ b0,
    const float* __restrict__ w1, const float* __restrict__ b1,
    const float* __restrict__ wxyz, const float* __restrict__ bxyz,
    const int* __restrict__ cnt, const int* __restrict__ ovf,
    const float4* __restrict__ buckets, const float4* __restrict__ featT,
    int use_grid, int use_ft,
    float* __restrict__ out)
{
    const int lane = threadIdx.x & 63;
    const int wid  = threadIdx.x >> 6;
    const int q    = (blockIdx.x << 2) + wid;
    const int b    = q >> 12;
    const int m    = q & (MM - 1);

    __shared__ int s_idx[4][KK];
    __shared__ float4 s_rel[4][KK];                      // xyz = rel, w = wk
    __shared__ __align__(16) unsigned s_bm[4][NDW];      // 2KB bitmap per wave

    const float* xb = xyz + (size_t)b * NN * 3;
    const float qx = new_xyz[((size_t)b*MM + m)*3 + 0];
    const float qy = new_xyz[((size_t)b*MM + m)*3 + 1];
    const float qz = new_xyz[((size_t)b*MM + m)*3 + 2];
    const unsigned long long below = (1ull << lane) - 1ull;

    int nfound = 0, idx0 = 0;
    bool need_full = (use_grid == 0) || (use_grid && ovf[0] != 0);

    if (!need_full) {
        // clear this wave's bitmap (in-order DS pipe: completes before atomics below)
        uint4 z4 = make_uint4(0u, 0u, 0u, 0u);
        *(uint4*)&s_bm[wid][lane*8]     = z4;
        *(uint4*)&s_bm[wid][lane*8 + 4] = z4;

        int x0 = max(0, (int)floorf((qx - 0.1f)*10.0f - 1e-3f));
        int x1 = min(GD-1, (int)floorf((qx + 0.1f)*10.0f + 1e-3f));
        int y0 = max(0, (int)floorf((qy - 0.1f)*10.0f - 1e-3f));
        int y1 = min(GD-1, (int)floorf((qy + 0.1f)*10.0f + 1e-3f));
        int z0 = max(0, (int)floorf((qz - 0.1f)*10.0f - 1e-3f));
        int z1 = min(GD-1, (int)floorf((qz + 0.1f)*10.0f + 1e-3f));

        // ---- assign cells to lanes (wave-uniform loop), one parallel cnt load ----
        int myCell = -1, ncells = 0;
        for (int cx = x0; cx <= x1; ++cx)
        for (int cy = y0; cy <= y1; ++cy)
        for (int cz = z0; cz <= z1; ++cz) {
            if (lane == ncells) myCell = b*CPB + (cx*GD + cy)*GD + cz;
            ++ncells;
        }
        int myCnt = 0, myBase = 0;
        if (myCell >= 0) { myCnt = min(cnt[myCell], CAP); myBase = myCell*CAP; }

        __builtin_amdgcn_wave_barrier();

        // ---- independent per-cell point tests; hits set bits in the bitmap ----
        for (int c = 0; c < ncells; ++c) {
            int cc    = __builtin_amdgcn_readlane(myCnt, c);
            int cbase = __builtin_amdgcn_readlane(myBase, c);
            if (lane < cc) {
                float4 pt = buckets[cbase + lane];
                float dx = pt.x - qx, dy = pt.y - qy, dz = pt.z - qz;
                float d2 = dx*dx + dy*dy + dz*dz;
                if (d2 < R2) {
                    int id = __float_as_int(pt.w);
                    atomicOr(&s_bm[wid][id >> 5], 1u << (id & 31));
                }
            }
        }

        __builtin_amdgcn_wave_barrier();

        // ---- bitmap -> first K indices (ascending). lane owns dwords [8l, 8l+8) ----
        uint4 d0 = *(uint4*)&s_bm[wid][lane*8];
        uint4 d1 = *(uint4*)&s_bm[wid][lane*8 + 4];
        unsigned dw[8] = {d0.x, d0.y, d0.z, d0.w, d1.x, d1.y, d1.z, d1.w};
        int pc = 0;
        #pragma unroll
        for (int j = 0; j < 8; ++j) pc += __popc(dw[j]);
        int pre = pc;
        #pragma unroll
        for (int d = 1; d < 64; d <<= 1) {
            int t = __shfl_up(pre, d);
            if (lane >= d) pre += t;
        }
        int total = __shfl(pre, 63);
        int rank = pre - pc;                  // exclusive prefix
        nfound = min(total, KK);

        if (rank < KK) {
            #pragma unroll
            for (int j = 0; j < 8; ++j) {
                unsigned bits = dw[j];
                while (bits && rank < KK) {
                    int bpos = __builtin_ctz(bits);
                    s_idx[wid][rank] = ((lane*8 + j) << 5) + bpos;
                    bits &= bits - 1;
                    ++rank;
                }
            }
        }

        __builtin_amdgcn_wave_barrier();
        idx0 = (nfound > 0) ? s_idx[wid][0] : 0;
        __builtin_amdgcn_wave_barrier();
        if (lane >= nfound && lane < KK) s_idx[wid][lane] = idx0;
        __builtin_amdgcn_wave_barrier();
    }

    if (need_full) {
        int cntf = 0;
        for (int basep = 0; basep < NN; basep += 256) {
            float d2a[4];
            #pragma unroll
            for (int j = 0; j < 4; ++j) {
                int i = basep + (j << 6) + lane;
                float px = xb[i*3+0], py = xb[i*3+1], pz = xb[i*3+2];
                float dx = px - qx, dy = py - qy, dz = pz - qz;
                d2a[j] = dx*dx + dy*dy + dz*dz;
            }
            #pragma unroll
            for (int j = 0; j < 4; ++j) {
                bool hit = d2a[j] < R2;
                unsigned long long msk = __ballot(hit);
                if (hit) {
                    int pos = cntf + __popcll(msk & below);
                    if (pos < KK) s_idx[wid][pos] = basep + (j << 6) + lane;
                }
                cntf += __popcll(msk);
            }
            if (cntf >= KK) break;
        }
        nfound = cntf < KK ? cntf : KK;
        __builtin_amdgcn_wave_barrier();
        if (lane < KK) {
            int v = 0;
            if (nfound > 0) v = (lane < nfound) ? s_idx[wid][lane] : s_idx[wid][0];
            s_idx[wid][lane] = v;
        }
        __builtin_amdgcn_wave_barrier();
        idx0 = s_idx[wid][0];
    }

    // ---------- rel coords + normalized weights (k = lane&31) ----------
    {
        const int k = lane & 31;
        const int h = lane >> 5;
        const int ik = s_idx[wid][k];
        float px = xb[ik*3+0], py = xb[ik*3+1], pz = xb[ik*3+2];
        float rx = px - qx, ry = py - qy, rz = pz - qz;
        float dist = sqrtf(rx*rx + ry*ry + rz*rz);
        float recip = 1.0f / (dist + EPSV);
        float mult = (float)(1 + KK - nfound);
        float w = recip / ((ik == idx0) ? mult : 1.0f);
        float S = w;
        #pragma unroll
        for (int d = 1; d < 32; d <<= 1) S += __shfl_xor(S, d);
        float wk = (nfound > 0) ? (w / S) : 0.0f;
        if (h == 0) s_rel[wid][k] = make_float4(rx, ry, rz, wk);
    }
    __builtin_amdgcn_wave_barrier();

    // ---------- MFMA MLP: lane = (l15, quad) ----------
    const int l15 = lane & 15;
    const int quad = lane >> 4;
    const int ik0 = s_idx[wid][l15];
    const int ik1 = s_idx[wid][16 + l15];

    float g0[CCH], g1[CCH];
    if (use_ft) {
        const float4* f0 = featT + ((size_t)(b*NN + ik0)) * 4;
        const float4* f1 = featT + ((size_t)(b*NN + ik1)) * 4;
        #pragma unroll
        for (int c4 = 0; c4 < 4; ++c4) {
            float4 a = f0[c4], c = f1[c4];
            g0[c4*4+0] = a.x; g0[c4*4+1] = a.y; g0[c4*4+2] = a.z; g0[c4*4+3] = a.w;
            g1[c4*4+0] = c.x; g1[c4*4+1] = c.y; g1[c4*4+2] = c.z; g1[c4*4+3] = c.w;
        }
    } else {
        const float* fb = feat + (size_t)b * CCH * NN;
        #pragma unroll
        for (int c = 0; c < CCH; ++c) { g0[c] = fb[c*NN + ik0]; g1[c] = fb[c*NN + ik1]; }
    }

    // h0 channels [8q, 8q+8) for both neighbors -> A fragments (no transpose)
    short8 A0, A1;
    #pragma unroll
    for (int j = 0; j < 8; ++j) {
        const int o = (quad << 3) + j;
        const float* wr = w0 + o*CCH;
        float a0 = 0.f, a1 = 0.f;
        #pragma unroll
        for (int c = 0; c < CCH; ++c) { a0 += wr[c]*g0[c]; a1 += wr[c]*g1[c]; }
        float bo = b0[o];
        A0[j] = f2bf(fmaxf(a0 + bo, 0.0f));
        A1[j] = f2bf(fmaxf(a1 + bo, 0.0f));
    }

    // B fragments: w1[16u+l15][8q..8q+8)
    short8 Bf[4];
    #pragma unroll
    for (int u = 0; u < 4; ++u) {
        const float* wr = w1 + ((u << 4) + l15)*32 + (quad << 3);
        float4 p = *(const float4*)(wr);
        float4 r = *(const float4*)(wr + 4);
        short8 bb;
        bb[0]=f2bf(p.x); bb[1]=f2bf(p.y); bb[2]=f2bf(p.z); bb[3]=f2bf(p.w);
        bb[4]=f2bf(r.x); bb[5]=f2bf(r.y); bb[6]=f2bf(r.z); bb[7]=f2bf(r.w);
        Bf[u] = bb;
    }

    v4f zero4 = {0.f, 0.f, 0.f, 0.f};
    v4f D[2][4];
    #pragma unroll
    for (int u = 0; u < 4; ++u) {
        D[0][u] = __builtin_amdgcn_mfma_f32_16x16x32_bf16(A0, Bf[u], zero4, 0, 0, 0);
        D[1][u] = __builtin_amdgcn_mfma_f32_16x16x32_bf16(A1, Bf[u], zero4, 0, 0, 0);
    }

    // wk for this lane's 8 rows: k = 16t + 4*quad + r
    float wkv[2][4];
    #pragma unroll
    for (int t = 0; t < 2; ++t)
        #pragma unroll
        for (int r = 0; r < 4; ++r)
            wkv[t][r] = s_rel[wid][16*t + (quad << 2) + r].w;

    float* out2 = out + (size_t)BB*MM*3 + (size_t)b*96*MM;

    float Su[4];
    #pragma unroll
    for (int u = 0; u < 4; ++u) {
        const float b1O = b1[(u << 4) + l15];
        float s = 0.f;
        #pragma unroll
        for (int t = 0; t < 2; ++t)
            #pragma unroll
            for (int r = 0; r < 4; ++r)
                s += wkv[t][r] * fmaxf(D[t][u][r] + b1O, 0.0f);
        s += __shfl_xor(s, 16);
        s += __shfl_xor(s, 32);
        Su[u] = s;
    }
    float sout = (quad == 0) ? Su[0] : (quad == 1) ? Su[1] : (quad == 2) ? Su[2] : Su[3];
    out2[(32 + lane)*MM + m] = sout;   // O = 16*quad + l15 = lane

    // ---------- xyz branch: lane = channel c, halves split k, max-pool ----------
    {
        const int c = lane & 31;
        const int h = lane >> 5;
        const float wx0 = wxyz[c*3+0], wx1 = wxyz[c*3+1], wx2 = wxyz[c*3+2];
        const float bc = bxyz[c];
        float v = 0.0f;
        #pragma unroll
        for (int kk = 0; kk < 16; ++kk) {
            float4 hr = s_rel[wid][(h << 4) + kk];
            float t = bc + wx0*hr.x + wx1*hr.y + wx2*hr.z;
            v = fmaxf(v, fmaxf(t, 0.0f));
        }
        v = fmaxf(v, __shfl_xor(v, 32));
        if (h == 0) out2[c*MM + m] = v;
    }

    if (lane == 0) {
        float* o0 = out + ((size_t)b*MM + m)*3;
        o0[0] = qx; o0[1] = qy; o0[2] = qz;
    }
}

extern "C" void kernel_launch(void* const* d_in, const int* in_sizes, int n_in,
                              void* d_out, int out_size, void* d_ws, size_t ws_size,
                              hipStream_t stream) {
    const float* xyz     = (const float*)d_in[0];
    const float* new_xyz = (const float*)d_in[1];
    const float* feat    = (const float*)d_in[2];
    const float* w0      = (const float*)d_in[3];
    const float* b0      = (const float*)d_in[4];
    const float* w1      = (const float*)d_in[5];
    const float* b1      = (const float*)d_in[6];
    const float* wxyz    = (const float*)d_in[7];
    const float* bxyz    = (const float*)d_in[8];
    float* out = (float*)d_out;

    int* ovf = (int*)d_ws;
    int* cnt = (int*)((char*)d_ws + 64);
    float4* buckets = (float4*)((char*)d_ws + BUCKET_OFF);
    float4* featT   = (float4*)((char*)d_ws + FEATT_OFF);
    const int use_grid = (d_ws != nullptr && ws_size >= WS_GRID) ? 1 : 0;
    const int use_ft   = (d_ws != nullptr && ws_size >= WS_FT) ? 1 : 0;

    if (use_grid) {
        hipMemsetAsync(d_ws, 0, BUCKET_OFF, stream);
        hipLaunchKernelGGL(k_scatter, dim3((BB*NN+255)/256), dim3(256), 0, stream,
                           xyz, feat, cnt, ovf, buckets, featT, use_ft);
    }
    hipLaunchKernelGGL(grouper_fused, dim3((BB*MM)/4), dim3(256), 0, stream,
                       xyz, new_xyz, feat, w0, b0, w1, b1, wxyz, bxyz,
                       cnt, ovf, buckets, featT, use_grid, use_ft, out);
}